// Round 2
// baseline (46299.338 us; speedup 1.0000x reference)
//
#include <hip/hip_runtime.h>

typedef unsigned short u16;
typedef unsigned int   u32;

#define LTC_B 32
#define LTC_L 1024
#define LTC_D 512
#define LTC_H 512
#define GP 16              // workgroups per group (weight slices)
#define GB 16              // batches per group

typedef _Float16 f16x8  __attribute__((ext_vector_type(8)));
typedef _Float16 f16x2t __attribute__((ext_vector_type(2)));
typedef float    f32x4  __attribute__((ext_vector_type(4)));

static __device__ __forceinline__ u32 packh(float a, float b) {
    f16x2t p; p[0] = (_Float16)a; p[1] = (_Float16)b;
    return __builtin_bit_cast(u32, p);
}
static __device__ __forceinline__ float unplo(u32 w) {
    return (float)__builtin_bit_cast(f16x2t, w)[0];
}
static __device__ __forceinline__ float unphi(u32 w) {
    return (float)__builtin_bit_cast(f16x2t, w)[1];
}
static __device__ __forceinline__ float sigm(float x) {
    return 1.f / (1.f + __expf(-x));
}
static __device__ __forceinline__ float tanh_f(float x) {
    float e = __expf(2.f * x);          // inf-safe: e=inf -> 1, e=0 -> -1
    return 1.f - 2.f / (e + 1.f);
}
static __device__ __forceinline__ f16x8 cvt8(const float* p) {
    const float4 a = *(const float4*)p;
    const float4 b = *(const float4*)(p + 4);
    f16x8 r;
    r[0] = (_Float16)a.x; r[1] = (_Float16)a.y; r[2] = (_Float16)a.z; r[3] = (_Float16)a.w;
    r[4] = (_Float16)b.x; r[5] = (_Float16)b.y; r[6] = (_Float16)b.z; r[7] = (_Float16)b.w;
    return r;
}

// ---------------------------------------------------------------------------
// C[M,512](f16) = A[M,512](f32) . W[:,:512]^T(f32, row stride ldb) + bias(f32)
// 64x64 tile per wave, 4x4 MFMA 16x16x32 f16, direct-from-global fragments.
// ---------------------------------------------------------------------------
__global__ __launch_bounds__(256) void gemm_a32_c16(
    const float* __restrict__ A, const float* __restrict__ W, int ldb,
    const float* __restrict__ bias, u16* __restrict__ C)
{
    const int wave = threadIdx.x >> 6;
    const int lane = threadIdx.x & 63;
    const int tile = blockIdx.x * 4 + wave;
    const int nt = tile & 7;
    const int mt = tile >> 3;
    const int r16 = lane & 15;
    const int kq  = (lane >> 4) * 8;

    const float* ap = A + (size_t)(mt * 64 + r16) * LTC_D + kq;
    const float* wp = W + (size_t)(nt * 64 + r16) * ldb + kq;

    f32x4 acc[4][4];
    #pragma unroll
    for (int i = 0; i < 4; ++i)
        #pragma unroll
        for (int jj = 0; jj < 4; ++jj) acc[i][jj] = (f32x4){0.f, 0.f, 0.f, 0.f};

    for (int ks = 0; ks < 16; ++ks) {
        f16x8 af[4], bf[4];
        #pragma unroll
        for (int t = 0; t < 4; ++t) {
            af[t] = cvt8(ap + (size_t)t * 16 * LTC_D + ks * 32);
            bf[t] = cvt8(wp + (size_t)t * 16 * ldb  + ks * 32);
        }
        #pragma unroll
        for (int mi = 0; mi < 4; ++mi)
            #pragma unroll
            for (int ni = 0; ni < 4; ++ni)
                acc[mi][ni] = __builtin_amdgcn_mfma_f32_16x16x32_f16(
                    af[mi], bf[ni], acc[mi][ni], 0, 0, 0);
    }
    const int row = (lane >> 4) * 4;   // C/D: col=lane&15, row=(lane>>4)*4+reg
    const int col = lane & 15;
    #pragma unroll
    for (int ni = 0; ni < 4; ++ni) {
        const int n = nt * 64 + ni * 16 + col;
        const float bv = bias[n];
        #pragma unroll
        for (int mi = 0; mi < 4; ++mi)
            #pragma unroll
            for (int r = 0; r < 4; ++r) {
                _Float16 h = (_Float16)(acc[mi][ni][r] + bv);
                C[(size_t)(mt * 64 + mi * 16 + row + r) * LTC_H + n] =
                    __builtin_bit_cast(u16, h);
            }
    }
}

// ---------------------------------------------------------------------------
// C[M,512](f32) = A[M,512](f16) . W^T(f32, row stride 512) + bias(f32)
// ---------------------------------------------------------------------------
__global__ __launch_bounds__(256) void gemm_a16_c32(
    const u16* __restrict__ A, const float* __restrict__ W,
    const float* __restrict__ bias, float* __restrict__ C)
{
    const int wave = threadIdx.x >> 6;
    const int lane = threadIdx.x & 63;
    const int tile = blockIdx.x * 4 + wave;
    const int nt = tile & 7;
    const int mt = tile >> 3;
    const int r16 = lane & 15;
    const int kq  = (lane >> 4) * 8;

    const _Float16* ap = (const _Float16*)A + (size_t)(mt * 64 + r16) * LTC_D + kq;
    const float*    wp = W + (size_t)(nt * 64 + r16) * LTC_H + kq;

    f32x4 acc[4][4];
    #pragma unroll
    for (int i = 0; i < 4; ++i)
        #pragma unroll
        for (int jj = 0; jj < 4; ++jj) acc[i][jj] = (f32x4){0.f, 0.f, 0.f, 0.f};

    for (int ks = 0; ks < 16; ++ks) {
        f16x8 af[4], bf[4];
        #pragma unroll
        for (int t = 0; t < 4; ++t) {
            af[t] = *(const f16x8*)(ap + (size_t)t * 16 * LTC_D + ks * 32);
            bf[t] = cvt8(wp + (size_t)t * 16 * LTC_H + ks * 32);
        }
        #pragma unroll
        for (int mi = 0; mi < 4; ++mi)
            #pragma unroll
            for (int ni = 0; ni < 4; ++ni)
                acc[mi][ni] = __builtin_amdgcn_mfma_f32_16x16x32_f16(
                    af[mi], bf[ni], acc[mi][ni], 0, 0, 0);
    }
    const int row = (lane >> 4) * 4;
    const int col = lane & 15;
    #pragma unroll
    for (int ni = 0; ni < 4; ++ni) {
        const int n = nt * 64 + ni * 16 + col;
        const float bv = bias[n];
        #pragma unroll
        for (int mi = 0; mi < 4; ++mi)
            #pragma unroll
            for (int r = 0; r < 4; ++r)
                C[(size_t)(mt * 64 + mi * 16 + row + r) * LTC_H + n] =
                    acc[mi][ni][r] + bv;
    }
}

__global__ void init_sync(u32* s) { s[threadIdx.x] = 0; }

// ---------------------------------------------------------------------------
// Sequential ODE scan. 2 groups x 16 batches; each group = 16 WGs, WG wp owns
// W_rec rows [32wp,32wp+32) and Wg_h rows [32wp,32wp+32) resident in LDS (f16).
// Per sub-step: MFMA h(16x512,f16,LDS) . Wslice^T -> 16x64, elementwise update
// of owned h rows (fp32 regs), publish f16 pairs via agent-scope atomic stores,
// one device-scope generation barrier, all-gather h via agent atomic loads.
// Double-buffered h by parity. fwd overwrites consumed drive slots (f16).
// ---------------------------------------------------------------------------
__global__ __launch_bounds__(256) void ltc_scan(
    u32* __restrict__ drive,            // f16 pairs; rewritten with fwd
    const u32* __restrict__ gatex,      // f16 pairs
    const float* __restrict__ W_rec,
    const float* __restrict__ W_gate,
    const float* __restrict__ log_tau,
    u32* __restrict__ hbuf,             // [2 parity][2 group][16 b][256] u32
    u32* __restrict__ syncw,            // [g*128]=arrivals, [g*128+64]=gen
    float* __restrict__ hlast)
{
    const int g   = blockIdx.x >> 4;
    const int wp  = blockIdx.x & 15;
    const int tid = threadIdx.x;
    const int lane = tid & 63;
    const int wv   = tid >> 6;                 // n-tile 0..3 (0-1 rec, 2-3 gate)

    __shared__ u32 Wldsu[64][260];             // 64 rows x 512 f16, +pad
    __shared__ u32 hTu[16][260];               // 16 batches x 512 f16, +pad
    __shared__ float red[64][17];              // matvec results [n][b]

    // one-time: weight slice -> LDS (f16). Row r<32: W_rec[32wp+r]; else Wg_h.
    for (int r = 0; r < 64; ++r) {
        const float* src = (r < 32)
            ? (W_rec  + (size_t)(32 * wp + r) * LTC_H + 2 * tid)
            : (W_gate + (size_t)(32 * wp + r - 32) * (LTC_D + LTC_H) + LTC_D + 2 * tid);
        float2 w2 = *(const float2*)src;
        Wldsu[r][tid] = packh(w2.x, w2.y);
    }
    for (int i = tid; i < 16 * 260; i += 256) (&hTu[0][0])[i] = 0;   // h0 = 0
    __syncthreads();

    // per-thread owned h pair: batch b, rows jg0, jg0+1
    const int b   = tid & 15;
    const int jp  = tid >> 4;                  // 0..15
    const int jg0 = 32 * wp + 2 * jp;
    float h0 = 0.f, h1 = 0.f;
    const float stau0 = (1.f / 6.f) * __expf(-log_tau[jg0]);
    const float stau1 = (1.f / 6.f) * __expf(-log_tau[jg0 + 1]);
    const size_t dbase = (size_t)(g * GB + b) * LTC_L * 256 + 16 * wp + jp;

    const int am  = lane & 15;
    const int kq  = (lane >> 4) * 8;
    const _Float16* hrow = (const _Float16*)&hTu[am][0];
    const _Float16* wrow = (const _Float16*)&Wldsu[wv * 16 + am][0];
    u32* cnt = &syncw[g * 128];
    u32* gen = &syncw[g * 128 + 64];
    const int hbase_g = g * (GB * 256);

    u32 kp1 = 0;                               // global sub-step counter + 1
    for (int l = 0; l < LTC_L; ++l) {
        const u32 dw = drive[dbase + (size_t)l * 256];
        const u32 gw = gatex[dbase + (size_t)l * 256];
        const float d0 = unplo(dw), d1 = unphi(dw);
        const float gx0 = unplo(gw), gx1 = unphi(gw);
        #pragma unroll 1
        for (int s = 0; s < 6; ++s) {
            // ---- matvec: OUT[b][n] for my 64 rows, all 16 batches ----
            f32x4 acc0 = (f32x4){0.f,0.f,0.f,0.f}, acc1 = acc0;
            #pragma unroll
            for (int ks = 0; ks < 16; ks += 2) {
                f16x8 a0 = *(const f16x8*)(hrow + ks * 32 + kq);
                f16x8 b0 = *(const f16x8*)(wrow + ks * 32 + kq);
                f16x8 a1 = *(const f16x8*)(hrow + (ks + 1) * 32 + kq);
                f16x8 b1 = *(const f16x8*)(wrow + (ks + 1) * 32 + kq);
                acc0 = __builtin_amdgcn_mfma_f32_16x16x32_f16(a0, b0, acc0, 0, 0, 0);
                acc1 = __builtin_amdgcn_mfma_f32_16x16x32_f16(a1, b1, acc1, 0, 0, 0);
            }
            {
                const int n  = wv * 16 + (lane & 15);
                const int rb = (lane >> 4) * 4;
                #pragma unroll
                for (int r = 0; r < 4; ++r) red[n][rb + r] = acc0[r] + acc1[r];
            }
            __syncthreads();
            // ---- elementwise update of my 2 h rows ----
            const float rec0 = red[2 * jp][b],     gh0 = red[32 + 2 * jp][b];
            const float rec1 = red[2 * jp + 1][b], gh1 = red[32 + 2 * jp + 1][b];
            h0 += stau0 * (sigm(gx0 + gh0) * tanh_f(d0 + rec0) - h0);
            h1 += stau1 * (sigm(gx1 + gh1) * tanh_f(d1 + rec1) - h1);
            ++kp1;
            const int par = (int)(kp1 & 1u);
            const int hb  = par * (2 * GB * 256) + hbase_g;
            __hip_atomic_store(&hbuf[hb + b * 256 + 16 * wp + jp], packh(h0, h1),
                               __ATOMIC_RELEASE, __HIP_MEMORY_SCOPE_AGENT);
            __syncthreads();                   // drains each thread's store (vmcnt 0)
            if (tid == 0) {
                __threadfence();
                u32 arr = __hip_atomic_fetch_add(cnt, 1u, __ATOMIC_ACQ_REL,
                                                 __HIP_MEMORY_SCOPE_AGENT);
                if (arr == GP * kp1 - 1) {
                    __hip_atomic_store(gen, kp1, __ATOMIC_RELEASE,
                                       __HIP_MEMORY_SCOPE_AGENT);
                } else {
                    while (__hip_atomic_load(gen, __ATOMIC_ACQUIRE,
                                             __HIP_MEMORY_SCOPE_AGENT) < kp1)
                        __builtin_amdgcn_s_sleep(2);
                }
            }
            __syncthreads();
            // ---- all-gather h(k+1) into LDS ----
            #pragma unroll
            for (int i = 0; i < 16; ++i)
                hTu[i][tid] = __hip_atomic_load(&hbuf[hb + i * 256 + tid],
                                                __ATOMIC_RELAXED,
                                                __HIP_MEMORY_SCOPE_AGENT);
            __syncthreads();
        }
        drive[dbase + (size_t)l * 256] = packh(h0, h1);   // fwd, in-place
    }
    hlast[(size_t)(g * GB + b) * LTC_H + jg0]     = h0;
    hlast[(size_t)(g * GB + b) * LTC_H + jg0 + 1] = h1;
}

// ---------------------------------------------------------------------------
extern "C" void kernel_launch(void* const* d_in, const int* in_sizes, int n_in,
                              void* d_out, int out_size, void* d_ws, size_t ws_size,
                              hipStream_t stream)
{
    const float* x       = (const float*)d_in[0];
    const float* log_tau = (const float*)d_in[1];
    const float* W_in    = (const float*)d_in[2];
    const float* b_in    = (const float*)d_in[3];
    const float* W_rec   = (const float*)d_in[4];
    const float* W_gate  = (const float*)d_in[5];
    const float* b_gate  = (const float*)d_in[6];
    const float* W_out   = (const float*)d_in[7];
    const float* b_out   = (const float*)d_in[8];

    float* out   = (float*)d_out;                       // (32,1024,512) fp32
    float* hlast = out + (size_t)LTC_B * LTC_L * LTC_H; // (32,512) fp32

    u32* ws    = (u32*)d_ws;                   // 64 MB + 65 KB used
    u32* drive = ws;                           // 8388608 u32 (f16 pairs)
    u32* gatex = ws + 8388608;                 // 8388608 u32
    u32* hbuf  = ws + 16777216;                // 16384 u32
    u32* syncw = ws + 16777216 + 16384;        // 256 u32

    const int blocks = (LTC_B * LTC_L / 64) * (LTC_H / 64) / 4;   // 1024

    init_sync<<<1, 256, 0, stream>>>(syncw);
    gemm_a32_c16<<<blocks, 256, 0, stream>>>(x, W_in, LTC_D, b_in, (u16*)drive);
    gemm_a32_c16<<<blocks, 256, 0, stream>>>(x, W_gate, LTC_D + LTC_H, b_gate, (u16*)gatex);
    ltc_scan<<<LTC_B, 256, 0, stream>>>(drive, gatex, W_rec, W_gate, log_tau,
                                        hbuf, syncw, hlast);
    gemm_a16_c32<<<blocks, 256, 0, stream>>>((const u16*)drive, W_out, b_out, out);
}